// Round 1
// baseline (429.002 us; speedup 1.0000x reference)
//
#include <hip/hip_runtime.h>

#define N_NODES 100000
#define N_EDGES 1600000
#define D_FEAT 64

// One wave (64 lanes) per edge: lane f handles feature f.
// e = global_tid >> 6 is wave-uniform -> row/col/attr loads are broadcast;
// x-read and out-atomicAdd are 64x4B coalesced (one 256B segment each).
__global__ void spline_scatter_kernel(const float* __restrict__ x,
                                      const int* __restrict__ row_idx,
                                      const int* __restrict__ col_idx,
                                      const float* __restrict__ edge_attr,
                                      float* __restrict__ out,
                                      int n_edges) {
    long long t = (long long)blockIdx.x * blockDim.x + threadIdx.x;
    int e = (int)(t >> 6);
    int f = (int)(t & 63);
    if (e >= n_edges) return;

    int r = row_idx[e];
    int c = col_idx[e];
    float w = expf(-edge_attr[e]);

    float v = w * x[(long long)c * D_FEAT + f];
    atomicAdd(&out[(long long)r * D_FEAT + f], v);
}

extern "C" void kernel_launch(void* const* d_in, const int* in_sizes, int n_in,
                              void* d_out, int out_size, void* d_ws, size_t ws_size,
                              hipStream_t stream) {
    const float* x        = (const float*)d_in[0];
    const int*   eidx     = (const int*)d_in[1];   // flat (2, E): [row | col]
    const float* attr     = (const float*)d_in[2];
    float*       out      = (float*)d_out;

    const int n_edges = in_sizes[2];               // E = 1,600,000
    const int*  row = eidx;
    const int*  col = eidx + n_edges;

    // Harness poisons d_out with 0xAA; we accumulate, so zero it first.
    hipMemsetAsync(out, 0, (size_t)out_size * sizeof(float), stream);

    const int threads = 256;                        // 4 edges per block
    const long long total = (long long)n_edges * 64;
    const int blocks = (int)((total + threads - 1) / threads);
    spline_scatter_kernel<<<blocks, threads, 0, stream>>>(x, row, col, attr, out, n_edges);
}

// Round 2
// 424.647 us; speedup vs baseline: 1.0103x; 1.0103x over previous
//
#include <hip/hip_runtime.h>

#define N_NODES_C 100000
#define D_FEAT 64

// ---------------- fallback (round-1) atomic kernel ----------------
__global__ void spline_scatter_atomic(const float* __restrict__ x,
                                      const int* __restrict__ row_idx,
                                      const int* __restrict__ col_idx,
                                      const float* __restrict__ edge_attr,
                                      float* __restrict__ out,
                                      int n_edges) {
    long long t = (long long)blockIdx.x * blockDim.x + threadIdx.x;
    int e = (int)(t >> 6);
    int f = (int)(t & 63);
    if (e >= n_edges) return;
    int r = row_idx[e];
    int c = col_idx[e];
    float w = expf(-edge_attr[e]);
    atomicAdd(&out[(long long)r * D_FEAT + f], w * x[(long long)c * D_FEAT + f]);
}

// ---------------- CSR-build pipeline ----------------

// K1: histogram of destination rows
__global__ void hist_kernel(const int* __restrict__ row_idx, int* __restrict__ counts,
                            int n_edges) {
    int e = blockIdx.x * blockDim.x + threadIdx.x;
    if (e < n_edges) atomicAdd(&counts[row_idx[e]], 1);
}

// K2: single-block exclusive scan of counts[n] -> start[n+1], cursor[n]
__global__ void scan_kernel(const int* __restrict__ counts, int* __restrict__ start,
                            int* __restrict__ cursor, int n) {
    __shared__ int wave_sums[16];
    __shared__ int carry_s;
    const int tid = threadIdx.x;          // 1024 threads = 16 waves
    const int lane = tid & 63;
    const int wid = tid >> 6;
    if (tid == 0) carry_s = 0;
    __syncthreads();
    for (int base = 0; base < n; base += 1024) {
        int i = base + tid;
        int v = (i < n) ? counts[i] : 0;
        // inclusive scan within wave
        int inc = v;
        #pragma unroll
        for (int d = 1; d < 64; d <<= 1) {
            int t = __shfl_up(inc, d, 64);
            if (lane >= d) inc += t;
        }
        if (lane == 63) wave_sums[wid] = inc;
        __syncthreads();
        if (tid == 0) {
            int s = carry_s;
            #pragma unroll
            for (int k = 0; k < 16; ++k) { int t = wave_sums[k]; wave_sums[k] = s; s += t; }
            carry_s = s;
        }
        __syncthreads();
        int excl = inc - v + wave_sums[wid];
        if (i < n) { start[i] = excl; cursor[i] = excl; }
        __syncthreads();
    }
    if (tid == 0) start[n] = carry_s;
}

// K3: bucket-scatter edges into destination order: colw[pos] = {col, w}
__global__ void bucket_kernel(const int* __restrict__ row_idx,
                              const int* __restrict__ col_idx,
                              const float* __restrict__ edge_attr,
                              int* __restrict__ cursor,
                              int2* __restrict__ colw,
                              int n_edges) {
    int e = blockIdx.x * blockDim.x + threadIdx.x;
    if (e >= n_edges) return;
    int r = row_idx[e];
    int c = col_idx[e];
    float w = expf(-edge_attr[e]);
    int pos = atomicAdd(&cursor[r], 1);
    colw[pos] = make_int2(c, __float_as_int(w));
}

// K4: one wave per node: gather + register accumulate, single plain store
__global__ void gather_accum_kernel(const float* __restrict__ x,
                                    const int* __restrict__ start,
                                    const int2* __restrict__ colw,
                                    float* __restrict__ out,
                                    int n_nodes) {
    int node = blockIdx.x * (blockDim.x >> 6) + (threadIdx.x >> 6);
    int lane = threadIdx.x & 63;
    if (node >= n_nodes) return;
    int b = start[node];
    int e = start[node + 1];
    float acc = 0.0f;
    int j = b;
    for (; j + 3 < e; j += 4) {
        int2 c0 = colw[j], c1 = colw[j + 1], c2 = colw[j + 2], c3 = colw[j + 3];
        float x0 = x[(size_t)c0.x * D_FEAT + lane];
        float x1 = x[(size_t)c1.x * D_FEAT + lane];
        float x2 = x[(size_t)c2.x * D_FEAT + lane];
        float x3 = x[(size_t)c3.x * D_FEAT + lane];
        acc += __int_as_float(c0.y) * x0;
        acc += __int_as_float(c1.y) * x1;
        acc += __int_as_float(c2.y) * x2;
        acc += __int_as_float(c3.y) * x3;
    }
    for (; j < e; ++j) {
        int2 c0 = colw[j];
        acc += __int_as_float(c0.y) * x[(size_t)c0.x * D_FEAT + lane];
    }
    out[(size_t)node * D_FEAT + lane] = acc;
}

extern "C" void kernel_launch(void* const* d_in, const int* in_sizes, int n_in,
                              void* d_out, int out_size, void* d_ws, size_t ws_size,
                              hipStream_t stream) {
    const float* x    = (const float*)d_in[0];
    const int*   eidx = (const int*)d_in[1];   // flat (2, E): [row | col]
    const float* attr = (const float*)d_in[2];
    float*       out  = (float*)d_out;

    const int n_edges = in_sizes[2];
    const int n_nodes = N_NODES_C;
    const int* row = eidx;
    const int* col = eidx + n_edges;

    // workspace layout (bytes):
    //   colw   : int2[E]      at 0
    //   counts : int[N]       at colw_end
    //   start  : int[N+1]
    //   cursor : int[N]
    size_t off_colw   = 0;
    size_t off_counts = off_colw + (size_t)n_edges * sizeof(int2);
    size_t off_start  = off_counts + (size_t)n_nodes * sizeof(int);
    size_t off_cursor = off_start + (size_t)(n_nodes + 1) * sizeof(int);
    size_t ws_needed  = off_cursor + (size_t)n_nodes * sizeof(int);

    if (ws_size < ws_needed) {
        // fallback: round-1 atomic kernel
        hipMemsetAsync(out, 0, (size_t)out_size * sizeof(float), stream);
        const long long total = (long long)n_edges * 64;
        const int blocks = (int)((total + 255) / 256);
        spline_scatter_atomic<<<blocks, 256, 0, stream>>>(x, row, col, attr, out, n_edges);
        return;
    }

    char* ws = (char*)d_ws;
    int2* colw   = (int2*)(ws + off_colw);
    int*  counts = (int*)(ws + off_counts);
    int*  start  = (int*)(ws + off_start);
    int*  cursor = (int*)(ws + off_cursor);

    hipMemsetAsync(counts, 0, (size_t)n_nodes * sizeof(int), stream);

    const int eb = (n_edges + 255) / 256;
    hist_kernel<<<eb, 256, 0, stream>>>(row, counts, n_edges);
    scan_kernel<<<1, 1024, 0, stream>>>(counts, start, cursor, n_nodes);
    bucket_kernel<<<eb, 256, 0, stream>>>(row, col, attr, cursor, colw, n_edges);

    const int waves_per_block = 4;                 // 256 threads
    const int nb = (n_nodes + waves_per_block - 1) / waves_per_block;
    gather_accum_kernel<<<nb, 256, 0, stream>>>(x, start, colw, out, n_nodes);
}